// Round 14
// baseline (364.597 us; speedup 1.0000x reference)
//
#include <hip/hip_runtime.h>
#include <hip/hip_bf16.h>
#include <cstdint>

typedef __attribute__((ext_vector_type(8))) short bf16x8;
typedef __attribute__((ext_vector_type(4))) float f32x4;
typedef unsigned short u16;

constexpr int B = 2, S = 2048, D = 2048, H = 16, HD = 128;
constexpr int M = B * S;                 // 4096 rows
constexpr int NQKU = 6144;               // qku row stride (u at col 4096)
constexpr float SCALE = 0.08838834764831845f;  // 1/sqrt(128)

static __device__ __forceinline__ float b2f(u16 u) {
    union { float f; uint32_t i; } v; v.i = ((uint32_t)u) << 16; return v.f;
}
static __device__ __forceinline__ u16 f2b(float f) {
    union { float f; uint32_t i; } v; v.f = f;
    uint32_t x = v.i;
    return (u16)((x + 0x7FFFu + ((x >> 16) & 1u)) >> 16);
}

__device__ __forceinline__ void gll16(const void* g, void* l) {
    __builtin_amdgcn_global_load_lds(
        (const __attribute__((address_space(1))) uint32_t*)g,
        (__attribute__((address_space(3))) uint32_t*)l, 16, 0, 0);
}

#define BAR() do { asm volatile("" ::: "memory"); __builtin_amdgcn_s_barrier(); \
                   asm volatile("" ::: "memory"); } while (0)

// ---------------- silu(x) f32 -> bf16 ----------------
__global__ __launch_bounds__(256) void silu_cast(const float* __restrict__ x,
                                                 u16* __restrict__ h, int n) {
    int i = (blockIdx.x * 256 + threadIdx.x) * 4;
    if (i >= n) return;
    float4 v = *(const float4*)(x + i);
    ushort4 o;
    o.x = f2b(v.x / (1.f + __expf(-v.x)));
    o.y = f2b(v.y / (1.f + __expf(-v.y)));
    o.z = f2b(v.z / (1.f + __expf(-v.z)));
    o.w = f2b(v.w / (1.f + __expf(-v.w)));
    *(ushort4*)(h + i) = o;
}

// ---------------- 5 weights (K,N) f32 -> wT (N,K) bf16, one launch ----------------
__global__ __launch_bounds__(256)
void wcast5(const float* __restrict__ w0, const float* __restrict__ w1,
            const float* __restrict__ w2, const float* __restrict__ w3,
            const float* __restrict__ w4, u16* __restrict__ wT) {
    __shared__ float t[64][65];
    int z = blockIdx.z;
    const float* w = (z == 0) ? w0 : (z == 1) ? w1 : (z == 2) ? w2 : (z == 3) ? w3 : w4;
    u16* dst = wT + (size_t)z * D * D;
    int tx = threadIdx.x & 63, ty = threadIdx.x >> 6;
    int kb = blockIdx.y * 64, nb = blockIdx.x * 64;
    for (int r = ty; r < 64; r += 4)
        t[r][tx] = w[(size_t)(kb + r) * D + nb + tx];
    __syncthreads();
    for (int r = ty; r < 64; r += 4)
        dst[(size_t)(nb + r) * D + kb + tx] = f2b(t[tx][r]);
}

// ============ fused QKUV GEMM: 256x256 tile, BK=64, 8 waves ============
// Epilogue: q,k tiles get RoPE in-register -> qr/kr (B,H,S,HD);
// u tiles -> qku (stride NQKU); v tiles -> vt (B,H,HD,S).
__global__ __launch_bounds__(512, 2)
void gemm_qkuv(const u16* __restrict__ A, const u16* __restrict__ BT,
               u16* __restrict__ qku, u16* __restrict__ vt,
               u16* __restrict__ qr, u16* __restrict__ kr,
               const float* __restrict__ fc, const float* __restrict__ fs) {
    __shared__ u16 lds[65536];
    const int tid = threadIdx.x;
    const int lane = tid & 63, wid = tid >> 6;
    const int wm = wid >> 2, wn = wid & 3;
    const int l16 = lane & 15, lq = lane >> 4;

    const int orig = blockIdx.x;
    const int swz = (orig & 7) * 64 + (orig >> 3);
    const int mt = swz & 15, nt = swz >> 4;
    const int m0 = mt * 256, n0 = nt * 256;

    const int srow = tid >> 2;
    const int ce = ((tid & 3) * 8) ^ (((tid >> 5) & 1) << 4);
    const int rdx = (lq * 16) ^ (((l16 >> 3) & 1) << 5);

    const u16* As0 = A + (size_t)(m0 + srow) * D + ce;
    const u16* Bs0 = BT + (size_t)(n0 + srow) * D + ce;

    {
        u16* dA = lds + wid * 512;
        u16* dB = lds + 16384 + wid * 512;
        gll16(As0,                    dA);
        gll16(As0 + (size_t)128 * D,  dA + 8192);
        gll16(Bs0,                    dB);
        gll16(Bs0 + (size_t)128 * D,  dB + 8192);
        gll16(As0 + 32,                    dA + 4096);
        gll16(As0 + 32 + (size_t)128 * D,  dA + 8192 + 4096);
        gll16(Bs0 + 32,                    dB + 4096);
        gll16(Bs0 + 32 + (size_t)128 * D,  dB + 8192 + 4096);
        u16* dA1 = lds + 32768 + wid * 512;
        u16* dB1 = lds + 32768 + 16384 + wid * 512;
        gll16(As0 + 64,                    dA1);
        gll16(As0 + 64 + (size_t)128 * D,  dA1 + 8192);
        gll16(Bs0 + 64,                    dB1);
        gll16(Bs0 + 64 + (size_t)128 * D,  dB1 + 8192);
    }
    asm volatile("s_waitcnt vmcnt(8)" ::: "memory");
    BAR();

    f32x4 acc[8][4] = {};
    bf16x8 a[8];
    const int rbB = (wn & 1) * 4096;

#define LOAD_A(kk)                                                            \
    _Pragma("unroll") for (int mi = 0; mi < 8; ++mi)                          \
        a[mi] = *(const bf16x8*)(Abase + (kk) * 8192 +                        \
                                 (mi * 16 + l16) * 64 + rdx);
#define LOAD_B(dst, nia, kk)                                                  \
    dst = *(const bf16x8*)(Bbase + (kk) * 8192 + rbB +                        \
                           ((nia) * 16 + l16) * 64 + rdx);
#define MFMA2(n0i, n1i)                                                       \
    __builtin_amdgcn_s_setprio(1);                                            \
    _Pragma("unroll") for (int mi = 0; mi < 8; ++mi) {                        \
        acc[mi][n0i] = __builtin_amdgcn_mfma_f32_16x16x32_bf16(a[mi], b0,     \
                            acc[mi][n0i], 0, 0, 0);                           \
        acc[mi][n1i] = __builtin_amdgcn_mfma_f32_16x16x32_bf16(a[mi], b1,     \
                            acc[mi][n1i], 0, 0, 0);                           \
    }                                                                          \
    __builtin_amdgcn_s_setprio(0);

    for (int kt = 0; kt < 32; ++kt) {
        const int buf = kt & 1;
        const char* Abase = (const char*)lds + buf * 65536 + wm * 16384;
        const char* Bbase = (const char*)lds + 32768 + buf * 65536 + (wn >> 1) * 16384;
        const bool st1 = (kt + 1) < 32;
        const bool st2 = (kt + 2) < 32;
        const u16* Asrc1 = As0 + (kt + 1) * 64;
        const u16* Bsrc1 = Bs0 + (kt + 1) * 64;
        const u16* Asrc2 = As0 + (kt + 2) * 64;
        const u16* Bsrc2 = Bs0 + (kt + 2) * 64;
        u16* dN = lds + (buf ^ 1) * 32768 + wid * 512;
        u16* dC = lds + buf * 32768 + wid * 512;
        bf16x8 b0, b1;

        LOAD_A(0);
        LOAD_B(b0, 0, 0);
        LOAD_B(b1, 1, 0);
        if (st1) { gll16(Asrc1 + 32, dN + 4096);
                   gll16(Asrc1 + 32 + (size_t)128 * D, dN + 8192 + 4096); }
        BAR();
        MFMA2(0, 1);
        BAR();
        LOAD_B(b0, 2, 0);
        LOAD_B(b1, 3, 0);
        if (st1) { gll16(Bsrc1 + 32, dN + 16384 + 4096);
                   gll16(Bsrc1 + 32 + (size_t)128 * D, dN + 16384 + 8192 + 4096); }
        BAR();
        MFMA2(2, 3);
        if (kt == 31) asm volatile("s_waitcnt vmcnt(0)" ::: "memory");
        else          asm volatile("s_waitcnt vmcnt(8)" ::: "memory");
        BAR();
        LOAD_A(1);
        LOAD_B(b0, 0, 1);
        LOAD_B(b1, 1, 1);
        if (st2) { gll16(Asrc2, dC);
                   gll16(Asrc2 + (size_t)128 * D, dC + 8192); }
        BAR();
        MFMA2(0, 1);
        BAR();
        LOAD_B(b0, 2, 1);
        LOAD_B(b1, 3, 1);
        if (st2) { gll16(Bsrc2, dC + 16384);
                   gll16(Bsrc2 + (size_t)128 * D, dC + 16384 + 8192); }
        BAR();
        MFMA2(2, 3);
        if (kt < 30)       asm volatile("s_waitcnt vmcnt(8)" ::: "memory");
        else if (kt == 30) asm volatile("s_waitcnt vmcnt(4)" ::: "memory");
        BAR();
    }
#undef LOAD_A
#undef LOAD_B
#undef MFMA2

    if (n0 >= NQKU) {   // V tiles -> vt (B,H,HD,S)
#pragma unroll
        for (int mi = 0; mi < 8; ++mi)
#pragma unroll
            for (int ni = 0; ni < 4; ++ni) {
                int c = n0 - NQKU + wn * 64 + ni * 16 + l16;
                int hh = c >> 7, d = c & 127;
                int row0 = m0 + wm * 128 + mi * 16 + lq * 4;
                int bb = row0 >> 11, s0 = row0 & 2047;
                ushort4 pk = make_ushort4(f2b(acc[mi][ni][0]), f2b(acc[mi][ni][1]),
                                          f2b(acc[mi][ni][2]), f2b(acc[mi][ni][3]));
                *(ushort4*)(vt + (((size_t)(bb * H + hh) * HD + d) * S + s0)) = pk;
            }
    } else if (n0 >= 4096) {   // U tiles -> qku (stride NQKU)
#pragma unroll
        for (int mi = 0; mi < 8; ++mi)
#pragma unroll
            for (int ni = 0; ni < 4; ++ni)
#pragma unroll
                for (int r = 0; r < 4; ++r) {
                    int row = m0 + wm * 128 + mi * 16 + lq * 4 + r;
                    int col = n0 + wn * 64 + ni * 16 + l16;
                    qku[(size_t)row * NQKU + col] = f2b(acc[mi][ni][r]);
                }
    } else {   // Q or K tiles: RoPE in-register -> qr / kr (B,H,S,HD)
        u16* dst = (n0 < 2048) ? qr : kr;
#pragma unroll
        for (int mi = 0; mi < 8; ++mi)
#pragma unroll
            for (int ni = 0; ni < 4; ++ni) {
                int c = (n0 & 2047) + wn * 64 + ni * 16 + l16;
                int hh = c >> 7, d = c & 127;
                int pp = d >> 1;
                float sgn = (d & 1) ? 1.f : -1.f;
                int row0 = m0 + wm * 128 + mi * 16 + lq * 4;
                int bb = row0 >> 11, s0 = row0 & 2047;
                u16* dp = dst + ((size_t)(bb * H + hh) * S + s0) * HD + d;
#pragma unroll
                for (int r = 0; r < 4; ++r) {
                    float me = acc[mi][ni][r];
                    float pt = __shfl_xor(me, 1, 64);   // pair value (d^1)
                    int sgl = s0 + r;
                    float cs = fc[sgl * 64 + pp], sn = fs[sgl * 64 + pp];
                    dp[(size_t)r * HD] = f2b(me * cs + sgn * pt * sn);
                }
            }
    }
}

// ---------------- GEMM (m97 structure): f32 out ----------------
__global__ __launch_bounds__(256)
void gemm_bt_f32(const u16* __restrict__ A, const u16* __restrict__ BT,
                 float* __restrict__ out, int lda, int ldc, int Kk) {
    __shared__ u16 As[128 * 32];
    __shared__ u16 Bs[128 * 32];
    const int tid = threadIdx.x;
    const int lane = tid & 63, w = tid >> 6;
    const int wm = w >> 1, wn = w & 1;
    const int l16 = lane & 15, lq = lane >> 4;
    const int m0 = blockIdx.y * 128, n0 = blockIdx.x * 128;
    const int rs = lane >> 2;
    const int cs = (lane & 3) * 8;
    f32x4 acc[4][4] = {};

    const u16* Ab = A + (size_t)(m0 + w * 32 + rs) * lda + cs;
    const u16* Bb = BT + (size_t)(n0 + w * 32 + rs) * Kk + cs;
    u16* Al = As + w * 32 * 32;
    u16* Bl = Bs + w * 32 * 32;

    for (int k0 = 0; k0 < Kk; k0 += 32) {
        gll16(Ab + k0, Al);
        gll16(Ab + k0 + (size_t)16 * lda, Al + 16 * 32);
        gll16(Bb + k0, Bl);
        gll16(Bb + k0 + (size_t)16 * Kk, Bl + 16 * 32);
        __syncthreads();
        bf16x8 af[4], bfr[4];
#pragma unroll
        for (int mi = 0; mi < 4; mi++)
            af[mi] = *(const bf16x8*)(As + (wm * 64 + mi * 16 + l16) * 32 + lq * 8);
#pragma unroll
        for (int ni = 0; ni < 4; ni++)
            bfr[ni] = *(const bf16x8*)(Bs + (wn * 64 + ni * 16 + l16) * 32 + lq * 8);
#pragma unroll
        for (int mi = 0; mi < 4; mi++)
#pragma unroll
            for (int ni = 0; ni < 4; ni++)
                acc[mi][ni] = __builtin_amdgcn_mfma_f32_16x16x32_bf16(
                    af[mi], bfr[ni], acc[mi][ni], 0, 0, 0);
        __syncthreads();
    }
#pragma unroll
    for (int mi = 0; mi < 4; mi++)
#pragma unroll
        for (int ni = 0; ni < 4; ni++)
#pragma unroll
            for (int r = 0; r < 4; r++) {
                int row = m0 + wm * 64 + mi * 16 + lq * 4 + r;
                int col = n0 + wn * 64 + ni * 16 + l16;
                out[(size_t)row * ldc + col] = acc[mi][ni][r];
            }
}

// ======== causal silu-attention: QBLK=256, KBLK=64, double-buffered K/V ========
// 128 blocks x 512 threads. Waves: wq (4 bands x 64q) x wk2 (2 slices).
// Pairing tq <-> 7-tq gives uniform 36 k-iters. Exact vmcnt ledger: prologue 4,
// steady 6, tails 4/2/0. Output bf16 into qku q-cols.
__global__ __launch_bounds__(512, 1)
void hstu_attn(const u16* __restrict__ qr, const u16* __restrict__ kr,
               const u16* __restrict__ vt, u16* __restrict__ attb) {
    __shared__ u16 k_l[2 * 8192];    // 2 x [64 k][128 d] swizzled
    __shared__ u16 v_l[2 * 8192];    // 2 x [128 d][64 s] swizzled
    __shared__ u16 s_l[256 * 72];    // [256 q][64 k + 8]
    const int id = blockIdx.x;                       // 0..127
    const int bh = (id & 7) * 4 + ((id >> 3) & 3);   // 4 heads per XCD
    const int slot = id >> 5;                        // 0..3
    const int b = bh >> 4, h = bh & 15;
    const int tid = threadIdx.x, lane = tid & 63, w = tid >> 6;
    const int l16 = lane & 15, lq = lane >> 4;
    const int wq = w >> 1, wk2 = w & 1;

    const u16* kb = kr + (size_t)bh * S * HD;
    const u16* vb = vt + (size_t)bh * HD * S;
    const u16* qb = qr + (size_t)bh * S * HD;

#define STAGE_K(k0_, bf_) do {                                                \
    _Pragma("unroll") for (int r_ = 0; r_ < 2; ++r_) {                        \
        int i_ = tid + r_ * 512;                                              \
        int row_ = i_ >> 4, iu_ = i_ & 15;                                    \
        int uc_ = iu_ ^ (row_ & 7);                                           \
        gll16(kb + (size_t)((k0_) + row_) * HD + uc_ * 8,                     \
              k_l + (bf_) * 8192 + ((w * 64 + r_ * 512) << 3));               \
    } } while (0)
#define STAGE_V(k0_, bf_) do {                                                \
    _Pragma("unroll") for (int r_ = 0; r_ < 2; ++r_) {                        \
        int i_ = tid + r_ * 512;                                              \
        int d_ = i_ >> 3, iu_ = i_ & 7;                                       \
        int uc_ = iu_ ^ (d_ & 7);                                             \
        gll16(vb + (size_t)d_ * S + (k0_) + uc_ * 8,                          \
              v_l + (bf_) * 8192 + ((w * 64 + r_ * 512) << 3));               \
    } } while (0)

    for (int pass = 0; pass < 2; ++pass) {
        const int tq = pass ? (7 - slot) : slot;
        const int q0 = tq * 256;
        const int kmax = 4 * tq + 3;       // inclusive; iters 0..kmax

        bf16x8 qf[4][4];
#pragma unroll
        for (int mi = 0; mi < 4; ++mi)
#pragma unroll
            for (int kk = 0; kk < 4; ++kk)
                qf[mi][kk] = *(const bf16x8*)(qb +
                    (size_t)(q0 + wq * 64 + mi * 16 + l16) * HD + kk * 32 + lq * 8);
        f32x4 acco[4][4] = {};

        STAGE_K(0, 0);
        STAGE_V(0, 0);
        STAGE_K(64, 1);
        STAGE_V(64, 1);
        asm volatile("s_waitcnt vmcnt(4)" ::: "memory");   // qf + K0,V0 landed
        BAR();

        for (int kt = 0; kt <= kmax; ++kt) {
            const int k0 = kt * 64;
            const int buf = kt & 1;
            // ---- QK^T: S[64q (wq)][32k (wk2)] ----
            f32x4 accs[4][2] = {};
            __builtin_amdgcn_s_setprio(1);
#pragma unroll
            for (int kk = 0; kk < 4; ++kk)
#pragma unroll
                for (int ni = 0; ni < 2; ++ni) {
                    int row = wk2 * 32 + ni * 16 + l16;
                    bf16x8 kf = *(const bf16x8*)(k_l + buf * 8192 + row * 128 +
                                ((kk * 32 + lq * 8) ^ ((row & 7) << 3)));
#pragma unroll
                    for (int mi = 0; mi < 4; ++mi)
                        accs[mi][ni] = __builtin_amdgcn_mfma_f32_16x16x32_bf16(
                            qf[mi][kk], kf, accs[mi][ni], 0, 0, 0);
                }
            __builtin_amdgcn_s_setprio(0);
            // silu + causal mask -> s_l
            const bool dg = (kt >= 4 * tq);
#pragma unroll
            for (int mi = 0; mi < 4; ++mi)
#pragma unroll
                for (int ni = 0; ni < 2; ++ni)
#pragma unroll
                    for (int r = 0; r < 4; ++r) {
                        int qrow = wq * 64 + mi * 16 + lq * 4 + r;
                        int krow = wk2 * 32 + ni * 16 + l16;
                        float vv = accs[mi][ni][r] * SCALE;
                        vv = (!dg || (k0 + krow <= q0 + qrow))
                                 ? vv * __builtin_amdgcn_rcpf(1.f + __expf(-vv))
                                 : 0.f;
                        s_l[qrow * 72 + krow] = f2b(vv);
                    }
            BAR();                                // k_l[buf] reads + s_l writes done
            if (kt + 2 <= kmax) STAGE_K((kt + 2) * 64, buf);
            if (kt + 2 <= kmax)
                asm volatile("s_waitcnt vmcnt(6)" ::: "memory");  // V(kt) landed
            else if (kt == kmax - 1)
                asm volatile("s_waitcnt vmcnt(4)" ::: "memory");
            else
                asm volatile("s_waitcnt vmcnt(0)" ::: "memory");
            BAR();                                // v_l[buf] + s_l visible
            // ---- PV: out[64q (wq)][64d (wk2)] over 64 s ----
            __builtin_amdgcn_s_setprio(1);
#pragma unroll
            for (int kk = 0; kk < 2; ++kk) {
                bf16x8 sf[4];
#pragma unroll
                for (int mi = 0; mi < 4; ++mi)
                    sf[mi] = *(const bf16x8*)(s_l + (wq * 64 + mi * 16 + l16) * 72 +
                                              kk * 32 + lq * 8);
#pragma unroll
                for (int ni = 0; ni < 4; ++ni) {
                    int row = wk2 * 64 + ni * 16 + l16;   // d index
                    bf16x8 vf = *(const bf16x8*)(v_l + buf * 8192 + row * 64 +
                                (((kk * 4 + lq) ^ (row & 7)) << 3));
#pragma unroll
                    for (int mi = 0; mi < 4; ++mi)
                        acco[mi][ni] = __builtin_amdgcn_mfma_f32_16x16x32_bf16(
                            sf[mi], vf, acco[mi][ni], 0, 0, 0);
                }
            }
            __builtin_amdgcn_s_setprio(0);
            BAR();                                // v_l[buf] + s_l reads done
            if (kt + 2 <= kmax) {
                STAGE_V((kt + 2) * 64, buf);
                asm volatile("s_waitcnt vmcnt(6)" ::: "memory");  // K(kt+1) landed
            } else if (kt == kmax - 1) {
                asm volatile("s_waitcnt vmcnt(2)" ::: "memory");  // K(kmax) landed
            }
            BAR();                                // k_l[buf^1](kt+1) visible
        }
        // epilogue: bf16 att rows into qku cols 0..2047 (stride NQKU)
#pragma unroll
        for (int mi = 0; mi < 4; ++mi)
#pragma unroll
            for (int ni = 0; ni < 4; ++ni)
#pragma unroll
                for (int r = 0; r < 4; ++r)
                    attb[(size_t)(b * S + q0 + wq * 64 + mi * 16 + lq * 4 + r) * NQKU +
                         h * HD + wk2 * 64 + ni * 16 + l16] = f2b(acco[mi][ni][r]);
    }
#undef STAGE_K
#undef STAGE_V
}

// ---------------- RMS-norm * norm_w * u (att bf16 in qku cols 0..2047) ----------------
__global__ __launch_bounds__(256)
void rms_mul(u16* __restrict__ qku, const float* __restrict__ nw) {
    int row = blockIdx.x;
    int tid = threadIdx.x;
    int col = tid * 8;
    u16 at[8];
    *(int4*)at = *(const int4*)(qku + (size_t)row * NQKU + col);
    float f[8];
    float ss = 0.f;
#pragma unroll
    for (int j = 0; j < 8; j++) { f[j] = b2f(at[j]); ss += f[j] * f[j]; }
#pragma unroll
    for (int off = 32; off > 0; off >>= 1) ss += __shfl_down(ss, off, 64);
    __shared__ float red[4];
    int lane = tid & 63, w = tid >> 6;
    if (lane == 0) red[w] = ss;
    __syncthreads();
    float rs = rsqrtf((red[0] + red[1] + red[2] + red[3]) * (1.f / D) + 1e-5f);
    u16* up = qku + (size_t)row * NQKU + 4096 + col;
    u16 ut[8];
    *(int4*)ut = *(const int4*)up;
    u16 o[8];
#pragma unroll
    for (int j = 0; j < 8; j++)
        o[j] = f2b(f[j] * rs * nw[col + j] * b2f(ut[j]));
    *(int4*)up = *(int4*)o;
}

extern "C" void kernel_launch(void* const* d_in, const int* in_sizes, int n_in,
                              void* d_out, int out_size, void* d_ws, size_t ws_size,
                              hipStream_t stream) {
    const float* x  = (const float*)d_in[0];
    const float* fc = (const float*)d_in[1];
    const float* fs = (const float*)d_in[2];
    const float* wq = (const float*)d_in[3];
    const float* wk = (const float*)d_in[4];
    const float* wv = (const float*)d_in[5];
    const float* wu = (const float*)d_in[6];
    const float* wo = (const float*)d_in[7];
    const float* nw = (const float*)d_in[8];
    float* out = (float*)d_out;

    char* ws = (char*)d_ws;
    const size_t WSZ = (size_t)D * D * sizeof(u16);      // 8.39 MB
    // layout (WSZ units): h[0,2) wT[2,7) qku[7,13) vt[13,15) k_r[15,17) q_r[17,19)
    u16* h_b  = (u16*)(ws);
    u16* wT   = (u16*)(ws + 2 * WSZ);                    // rows: q,k,u,v,o
    u16* qku  = (u16*)(ws + 7 * WSZ);                    // M x 6144 (att cols 0..2047, u at 4096)
    u16* vt   = (u16*)(ws + 13 * WSZ);                   // (B,H,HD,S)
    u16* k_r  = (u16*)(ws + 15 * WSZ);                   // (B,H,S,HD)
    u16* q_r  = (u16*)(ws + 17 * WSZ);                   // (B,H,S,HD)

    silu_cast<<<M * D / 1024, 256, 0, stream>>>(x, h_b, M * D);
    wcast5<<<dim3(32, 32, 5), 256, 0, stream>>>(wq, wk, wu, wv, wo, wT);

    // fused QKUV GEMM with RoPE'd q,k epilogue
    gemm_qkuv<<<512, 512, 0, stream>>>(h_b, wT, qku, vt, q_r, k_r, fc, fs);

    hstu_attn<<<128, 512, 0, stream>>>(q_r, k_r, vt, qku);
    rms_mul<<<M, 256, 0, stream>>>(qku, nw);
    gemm_bt_f32<<<dim3(D / 128, M / 128), 256, 0, stream>>>(
        qku + 4096, wT + 4 * (size_t)D * D, out, NQKU, D, D);
}

// Round 15
// 312.872 us; speedup vs baseline: 1.1653x; 1.1653x over previous
//
#include <hip/hip_runtime.h>
#include <hip/hip_bf16.h>
#include <cstdint>

typedef __attribute__((ext_vector_type(8))) short bf16x8;
typedef __attribute__((ext_vector_type(4))) float f32x4;
typedef unsigned short u16;

constexpr int B = 2, S = 2048, D = 2048, H = 16, HD = 128;
constexpr int M = B * S;                 // 4096 rows
constexpr int NQKU = 6144;               // qku row stride (u at col 4096)
constexpr float SCALE = 0.08838834764831845f;  // 1/sqrt(128)

static __device__ __forceinline__ float b2f(u16 u) {
    union { float f; uint32_t i; } v; v.i = ((uint32_t)u) << 16; return v.f;
}
static __device__ __forceinline__ u16 f2b(float f) {
    union { float f; uint32_t i; } v; v.f = f;
    uint32_t x = v.i;
    return (u16)((x + 0x7FFFu + ((x >> 16) & 1u)) >> 16);
}

__device__ __forceinline__ void gll16(const void* g, void* l) {
    __builtin_amdgcn_global_load_lds(
        (const __attribute__((address_space(1))) uint32_t*)g,
        (__attribute__((address_space(3))) uint32_t*)l, 16, 0, 0);
}

#define BAR() do { asm volatile("" ::: "memory"); __builtin_amdgcn_s_barrier(); \
                   asm volatile("" ::: "memory"); } while (0)

// ---------------- silu(x) f32 -> bf16 ----------------
__global__ __launch_bounds__(256) void silu_cast(const float* __restrict__ x,
                                                 u16* __restrict__ h, int n) {
    int i = (blockIdx.x * 256 + threadIdx.x) * 4;
    if (i >= n) return;
    float4 v = *(const float4*)(x + i);
    ushort4 o;
    o.x = f2b(v.x / (1.f + __expf(-v.x)));
    o.y = f2b(v.y / (1.f + __expf(-v.y)));
    o.z = f2b(v.z / (1.f + __expf(-v.z)));
    o.w = f2b(v.w / (1.f + __expf(-v.w)));
    *(ushort4*)(h + i) = o;
}

// ---------------- 5 weights (K,N) f32 -> wT (N,K) bf16, one launch ----------------
__global__ __launch_bounds__(256)
void wcast5(const float* __restrict__ w0, const float* __restrict__ w1,
            const float* __restrict__ w2, const float* __restrict__ w3,
            const float* __restrict__ w4, u16* __restrict__ wT) {
    __shared__ float t[64][65];
    int z = blockIdx.z;
    const float* w = (z == 0) ? w0 : (z == 1) ? w1 : (z == 2) ? w2 : (z == 3) ? w3 : w4;
    u16* dst = wT + (size_t)z * D * D;
    int tx = threadIdx.x & 63, ty = threadIdx.x >> 6;
    int kb = blockIdx.y * 64, nb = blockIdx.x * 64;
    for (int r = ty; r < 64; r += 4)
        t[r][tx] = w[(size_t)(kb + r) * D + nb + tx];
    __syncthreads();
    for (int r = ty; r < 64; r += 4)
        dst[(size_t)(nb + r) * D + kb + tx] = f2b(t[tx][r]);
}

// ============ fused QKUV GEMM: 256x256 tile, BK=64, 8 waves ============
// Epilogue: q,k tiles get RoPE in-register -> qr/kr (B,H,S,HD);
// u tiles -> qku (stride NQKU); v tiles -> vt TILED+PRE-SWIZZLED:
//   vt[((bh*32 + s>>6)*1024 + unit)*8 ...], unit = (d<<3)|(((s&63)>>3)^(d&7)),
//   elem offset (s&7). Attn then stages V as a contiguous linear 16KB read.
__global__ __launch_bounds__(512, 2)
void gemm_qkuv(const u16* __restrict__ A, const u16* __restrict__ BT,
               u16* __restrict__ qku, u16* __restrict__ vt,
               u16* __restrict__ qr, u16* __restrict__ kr,
               const float* __restrict__ fc, const float* __restrict__ fs) {
    __shared__ u16 lds[65536];
    const int tid = threadIdx.x;
    const int lane = tid & 63, wid = tid >> 6;
    const int wm = wid >> 2, wn = wid & 3;
    const int l16 = lane & 15, lq = lane >> 4;

    const int orig = blockIdx.x;
    const int swz = (orig & 7) * 64 + (orig >> 3);
    const int mt = swz & 15, nt = swz >> 4;
    const int m0 = mt * 256, n0 = nt * 256;

    const int srow = tid >> 2;
    const int ce = ((tid & 3) * 8) ^ (((tid >> 5) & 1) << 4);
    const int rdx = (lq * 16) ^ (((l16 >> 3) & 1) << 5);

    const u16* As0 = A + (size_t)(m0 + srow) * D + ce;
    const u16* Bs0 = BT + (size_t)(n0 + srow) * D + ce;

    {
        u16* dA = lds + wid * 512;
        u16* dB = lds + 16384 + wid * 512;
        gll16(As0,                    dA);
        gll16(As0 + (size_t)128 * D,  dA + 8192);
        gll16(Bs0,                    dB);
        gll16(Bs0 + (size_t)128 * D,  dB + 8192);
        gll16(As0 + 32,                    dA + 4096);
        gll16(As0 + 32 + (size_t)128 * D,  dA + 8192 + 4096);
        gll16(Bs0 + 32,                    dB + 4096);
        gll16(Bs0 + 32 + (size_t)128 * D,  dB + 8192 + 4096);
        u16* dA1 = lds + 32768 + wid * 512;
        u16* dB1 = lds + 32768 + 16384 + wid * 512;
        gll16(As0 + 64,                    dA1);
        gll16(As0 + 64 + (size_t)128 * D,  dA1 + 8192);
        gll16(Bs0 + 64,                    dB1);
        gll16(Bs0 + 64 + (size_t)128 * D,  dB1 + 8192);
    }
    asm volatile("s_waitcnt vmcnt(8)" ::: "memory");
    BAR();

    f32x4 acc[8][4] = {};
    bf16x8 a[8];
    const int rbB = (wn & 1) * 4096;

#define LOAD_A(kk)                                                            \
    _Pragma("unroll") for (int mi = 0; mi < 8; ++mi)                          \
        a[mi] = *(const bf16x8*)(Abase + (kk) * 8192 +                        \
                                 (mi * 16 + l16) * 64 + rdx);
#define LOAD_B(dst, nia, kk)                                                  \
    dst = *(const bf16x8*)(Bbase + (kk) * 8192 + rbB +                        \
                           ((nia) * 16 + l16) * 64 + rdx);
#define MFMA2(n0i, n1i)                                                       \
    __builtin_amdgcn_s_setprio(1);                                            \
    _Pragma("unroll") for (int mi = 0; mi < 8; ++mi) {                        \
        acc[mi][n0i] = __builtin_amdgcn_mfma_f32_16x16x32_bf16(a[mi], b0,     \
                            acc[mi][n0i], 0, 0, 0);                           \
        acc[mi][n1i] = __builtin_amdgcn_mfma_f32_16x16x32_bf16(a[mi], b1,     \
                            acc[mi][n1i], 0, 0, 0);                           \
    }                                                                          \
    __builtin_amdgcn_s_setprio(0);

    for (int kt = 0; kt < 32; ++kt) {
        const int buf = kt & 1;
        const char* Abase = (const char*)lds + buf * 65536 + wm * 16384;
        const char* Bbase = (const char*)lds + 32768 + buf * 65536 + (wn >> 1) * 16384;
        const bool st1 = (kt + 1) < 32;
        const bool st2 = (kt + 2) < 32;
        const u16* Asrc1 = As0 + (kt + 1) * 64;
        const u16* Bsrc1 = Bs0 + (kt + 1) * 64;
        const u16* Asrc2 = As0 + (kt + 2) * 64;
        const u16* Bsrc2 = Bs0 + (kt + 2) * 64;
        u16* dN = lds + (buf ^ 1) * 32768 + wid * 512;
        u16* dC = lds + buf * 32768 + wid * 512;
        bf16x8 b0, b1;

        LOAD_A(0);
        LOAD_B(b0, 0, 0);
        LOAD_B(b1, 1, 0);
        if (st1) { gll16(Asrc1 + 32, dN + 4096);
                   gll16(Asrc1 + 32 + (size_t)128 * D, dN + 8192 + 4096); }
        BAR();
        MFMA2(0, 1);
        BAR();
        LOAD_B(b0, 2, 0);
        LOAD_B(b1, 3, 0);
        if (st1) { gll16(Bsrc1 + 32, dN + 16384 + 4096);
                   gll16(Bsrc1 + 32 + (size_t)128 * D, dN + 16384 + 8192 + 4096); }
        BAR();
        MFMA2(2, 3);
        if (kt == 31) asm volatile("s_waitcnt vmcnt(0)" ::: "memory");
        else          asm volatile("s_waitcnt vmcnt(8)" ::: "memory");
        BAR();
        LOAD_A(1);
        LOAD_B(b0, 0, 1);
        LOAD_B(b1, 1, 1);
        if (st2) { gll16(Asrc2, dC);
                   gll16(Asrc2 + (size_t)128 * D, dC + 8192); }
        BAR();
        MFMA2(0, 1);
        BAR();
        LOAD_B(b0, 2, 1);
        LOAD_B(b1, 3, 1);
        if (st2) { gll16(Bsrc2, dC + 16384);
                   gll16(Bsrc2 + (size_t)128 * D, dC + 16384 + 8192); }
        BAR();
        MFMA2(2, 3);
        if (kt < 30)       asm volatile("s_waitcnt vmcnt(8)" ::: "memory");
        else if (kt == 30) asm volatile("s_waitcnt vmcnt(4)" ::: "memory");
        BAR();
    }
#undef LOAD_A
#undef LOAD_B
#undef MFMA2

    if (n0 >= NQKU) {   // V tiles -> vt tiled+pre-swizzled
#pragma unroll
        for (int mi = 0; mi < 8; ++mi)
#pragma unroll
            for (int ni = 0; ni < 4; ++ni) {
                int c = n0 - NQKU + wn * 64 + ni * 16 + l16;
                int hh = c >> 7, d = c & 127;
                int row0 = m0 + wm * 128 + mi * 16 + lq * 4;
                int bb = row0 >> 11, s0 = row0 & 2047;
                int st = s0 >> 6, sl = s0 & 63;
                int unit = (d << 3) | ((sl >> 3) ^ (d & 7));
                ushort4 pk = make_ushort4(f2b(acc[mi][ni][0]), f2b(acc[mi][ni][1]),
                                          f2b(acc[mi][ni][2]), f2b(acc[mi][ni][3]));
                *(ushort4*)(vt + ((size_t)((bb * H + hh) * 32 + st) * 1024 + unit) * 8 +
                            (sl & 7)) = pk;
            }
    } else if (n0 >= 4096) {   // U tiles -> qku (stride NQKU)
#pragma unroll
        for (int mi = 0; mi < 8; ++mi)
#pragma unroll
            for (int ni = 0; ni < 4; ++ni)
#pragma unroll
                for (int r = 0; r < 4; ++r) {
                    int row = m0 + wm * 128 + mi * 16 + lq * 4 + r;
                    int col = n0 + wn * 64 + ni * 16 + l16;
                    qku[(size_t)row * NQKU + col] = f2b(acc[mi][ni][r]);
                }
    } else {   // Q or K tiles: RoPE in-register -> qr / kr (B,H,S,HD)
        u16* dst = (n0 < 2048) ? qr : kr;
#pragma unroll
        for (int mi = 0; mi < 8; ++mi)
#pragma unroll
            for (int ni = 0; ni < 4; ++ni) {
                int c = (n0 & 2047) + wn * 64 + ni * 16 + l16;
                int hh = c >> 7, d = c & 127;
                int pp = d >> 1;
                float sgn = (d & 1) ? 1.f : -1.f;
                int row0 = m0 + wm * 128 + mi * 16 + lq * 4;
                int bb = row0 >> 11, s0 = row0 & 2047;
                u16* dp = dst + ((size_t)(bb * H + hh) * S + s0) * HD + d;
#pragma unroll
                for (int r = 0; r < 4; ++r) {
                    float me = acc[mi][ni][r];
                    float pt = __shfl_xor(me, 1, 64);   // pair value (d^1)
                    int sgl = s0 + r;
                    float cs = fc[sgl * 64 + pp], sn = fs[sgl * 64 + pp];
                    dp[(size_t)r * HD] = f2b(me * cs + sgn * pt * sn);
                }
            }
    }
}

// ---------------- GEMM (m97 structure): f32 out ----------------
__global__ __launch_bounds__(256)
void gemm_bt_f32(const u16* __restrict__ A, const u16* __restrict__ BT,
                 float* __restrict__ out, int lda, int ldc, int Kk) {
    __shared__ u16 As[128 * 32];
    __shared__ u16 Bs[128 * 32];
    const int tid = threadIdx.x;
    const int lane = tid & 63, w = tid >> 6;
    const int wm = w >> 1, wn = w & 1;
    const int l16 = lane & 15, lq = lane >> 4;
    const int m0 = blockIdx.y * 128, n0 = blockIdx.x * 128;
    const int rs = lane >> 2;
    const int cs = (lane & 3) * 8;
    f32x4 acc[4][4] = {};

    const u16* Ab = A + (size_t)(m0 + w * 32 + rs) * lda + cs;
    const u16* Bb = BT + (size_t)(n0 + w * 32 + rs) * Kk + cs;
    u16* Al = As + w * 32 * 32;
    u16* Bl = Bs + w * 32 * 32;

    for (int k0 = 0; k0 < Kk; k0 += 32) {
        gll16(Ab + k0, Al);
        gll16(Ab + k0 + (size_t)16 * lda, Al + 16 * 32);
        gll16(Bb + k0, Bl);
        gll16(Bb + k0 + (size_t)16 * Kk, Bl + 16 * 32);
        __syncthreads();
        bf16x8 af[4], bfr[4];
#pragma unroll
        for (int mi = 0; mi < 4; mi++)
            af[mi] = *(const bf16x8*)(As + (wm * 64 + mi * 16 + l16) * 32 + lq * 8);
#pragma unroll
        for (int ni = 0; ni < 4; ni++)
            bfr[ni] = *(const bf16x8*)(Bs + (wn * 64 + ni * 16 + l16) * 32 + lq * 8);
#pragma unroll
        for (int mi = 0; mi < 4; mi++)
#pragma unroll
            for (int ni = 0; ni < 4; ni++)
                acc[mi][ni] = __builtin_amdgcn_mfma_f32_16x16x32_bf16(
                    af[mi], bfr[ni], acc[mi][ni], 0, 0, 0);
        __syncthreads();
    }
#pragma unroll
    for (int mi = 0; mi < 4; mi++)
#pragma unroll
        for (int ni = 0; ni < 4; ni++)
#pragma unroll
            for (int r = 0; r < 4; r++) {
                int row = m0 + wm * 64 + mi * 16 + lq * 4 + r;
                int col = n0 + wn * 64 + ni * 16 + l16;
                out[(size_t)row * ldc + col] = acc[mi][ni][r];
            }
}

// ======== causal silu-attention: QBLK=128, KBLK=64, double-buffered K/V ========
// V source is tiled+pre-swizzled -> STAGE_V is a contiguous linear 16KB read.
__global__ __launch_bounds__(512, 1)
void hstu_attn(const u16* __restrict__ qr, const u16* __restrict__ kr,
               const u16* __restrict__ vt, u16* __restrict__ attb) {
    __shared__ u16 k_l[2 * 8192];    // 2 x [64 k][128 d] swizzled
    __shared__ u16 v_l[2 * 8192];    // 2 x [128 d][64 s] swizzled
    __shared__ u16 s_l[128 * 72];    // [128 q][64 k + 8]
    const int id = blockIdx.x;
    const int bh = (id & 7) * 4 + ((id >> 3) & 3);   // 4 heads per XCD
    const int slot = id >> 5;                        // 0..7
    const int b = bh >> 4, h = bh & 15;
    const int tid = threadIdx.x, lane = tid & 63, w = tid >> 6;
    const int l16 = lane & 15, lq = lane >> 4;
    const int wq = w >> 2, wk4 = w & 3;

    const u16* kb = kr + (size_t)bh * S * HD;
    const u16* vb = vt + (size_t)bh * S * HD;        // tiled: 32 tiles x 8192 u16
    const u16* qb = qr + (size_t)bh * S * HD;

#define STAGE_K(k0_, bf_) do {                                                \
    _Pragma("unroll") for (int r_ = 0; r_ < 2; ++r_) {                        \
        int i_ = tid + r_ * 512;                                              \
        int row_ = i_ >> 4, iu_ = i_ & 15;                                    \
        int uc_ = iu_ ^ (row_ & 7);                                           \
        gll16(kb + (size_t)((k0_) + row_) * HD + uc_ * 8,                     \
              k_l + (bf_) * 8192 + ((w * 64 + r_ * 512) << 3));               \
    } } while (0)
#define STAGE_V(k0_, bf_) do {                                                \
    _Pragma("unroll") for (int r_ = 0; r_ < 2; ++r_) {                        \
        int i_ = tid + r_ * 512;                                              \
        gll16(vb + ((size_t)((k0_) >> 6)) * 8192 + (size_t)i_ * 8,            \
              v_l + (bf_) * 8192 + ((w * 64 + r_ * 512) << 3));               \
    } } while (0)

    for (int pass = 0; pass < 2; ++pass) {
        const int tq = pass ? (15 - slot) : slot;
        const int q0 = tq * 128;
        const int kmax = 2 * tq + 1;

        bf16x8 qf[4][4];
#pragma unroll
        for (int mi = 0; mi < 4; ++mi)
#pragma unroll
            for (int kk = 0; kk < 4; ++kk)
                qf[mi][kk] = *(const bf16x8*)(qb +
                    (size_t)(q0 + wq * 64 + mi * 16 + l16) * HD + kk * 32 + lq * 8);
        f32x4 acco[4][2] = {};

        STAGE_K(0, 0);
        STAGE_V(0, 0);
        STAGE_K(64, 1);
        STAGE_V(64, 1);
        asm volatile("s_waitcnt vmcnt(8)" ::: "memory");
        BAR();

        for (int kt = 0; kt <= kmax; ++kt) {
            const int k0 = kt * 64;
            const int buf = kt & 1;
            f32x4 accs[4] = {};
            __builtin_amdgcn_s_setprio(1);
#pragma unroll
            for (int kk = 0; kk < 4; ++kk) {
                int row = wk4 * 16 + l16;
                bf16x8 kf = *(const bf16x8*)(k_l + buf * 8192 + row * 128 +
                            ((kk * 32 + lq * 8) ^ ((row & 7) << 3)));
#pragma unroll
                for (int mi = 0; mi < 4; ++mi)
                    accs[mi] = __builtin_amdgcn_mfma_f32_16x16x32_bf16(
                        qf[mi][kk], kf, accs[mi], 0, 0, 0);
            }
            __builtin_amdgcn_s_setprio(0);
            const bool dg = (kt >= 2 * tq);
#pragma unroll
            for (int mi = 0; mi < 4; ++mi)
#pragma unroll
                for (int r = 0; r < 4; ++r) {
                    int qrow = wq * 64 + mi * 16 + lq * 4 + r;
                    int krow = wk4 * 16 + l16;
                    float vv = accs[mi][r] * SCALE;
                    vv = (!dg || (k0 + krow <= q0 + qrow))
                             ? vv * __builtin_amdgcn_rcpf(1.f + __expf(-vv))
                             : 0.f;
                    s_l[qrow * 72 + krow] = f2b(vv);
                }
            BAR();
            if (kt + 2 <= kmax) STAGE_K((kt + 2) * 64, buf);
            if (kt <= kmax - 2)
                asm volatile("s_waitcnt vmcnt(12)" ::: "memory");
            else if (kt == kmax - 1)
                asm volatile("s_waitcnt vmcnt(8)" ::: "memory");
            else
                asm volatile("s_waitcnt vmcnt(0)" ::: "memory");
            BAR();
            __builtin_amdgcn_s_setprio(1);
#pragma unroll
            for (int kk = 0; kk < 2; ++kk) {
                bf16x8 sf[4];
#pragma unroll
                for (int mi = 0; mi < 4; ++mi)
                    sf[mi] = *(const bf16x8*)(s_l + (wq * 64 + mi * 16 + l16) * 72 +
                                              kk * 32 + lq * 8);
#pragma unroll
                for (int ni = 0; ni < 2; ++ni) {
                    int row = wk4 * 32 + ni * 16 + l16;
                    bf16x8 vf = *(const bf16x8*)(v_l + buf * 8192 + row * 64 +
                                (((kk * 4 + lq) ^ (row & 7)) << 3));
#pragma unroll
                    for (int mi = 0; mi < 4; ++mi)
                        acco[mi][ni] = __builtin_amdgcn_mfma_f32_16x16x32_bf16(
                            sf[mi], vf, acco[mi][ni], 0, 0, 0);
                }
            }
            __builtin_amdgcn_s_setprio(0);
            BAR();
            if (kt + 2 <= kmax) STAGE_V((kt + 2) * 64, buf);
            if (kt <= kmax - 2)
                asm volatile("s_waitcnt vmcnt(12)" ::: "memory");
            else if (kt == kmax - 1)
                asm volatile("s_waitcnt vmcnt(4)" ::: "memory");
            BAR();
        }
#pragma unroll
        for (int mi = 0; mi < 4; ++mi)
#pragma unroll
            for (int ni = 0; ni < 2; ++ni)
#pragma unroll
                for (int r = 0; r < 4; ++r)
                    attb[(size_t)(b * S + q0 + wq * 64 + mi * 16 + lq * 4 + r) * NQKU +
                         h * HD + wk4 * 32 + ni * 16 + l16] = f2b(acco[mi][ni][r]);
    }
#undef STAGE_K
#undef STAGE_V
}

// ---------------- RMS-norm * norm_w * u (att bf16 in qku cols 0..2047) ----------------
__global__ __launch_bounds__(256)
void rms_mul(u16* __restrict__ qku, const float* __restrict__ nw) {
    int row = blockIdx.x;
    int tid = threadIdx.x;
    int col = tid * 8;
    u16 at[8];
    *(int4*)at = *(const int4*)(qku + (size_t)row * NQKU + col);
    float f[8];
    float ss = 0.f;
#pragma unroll
    for (int j = 0; j < 8; j++) { f[j] = b2f(at[j]); ss += f[j] * f[j]; }
#pragma unroll
    for (int off = 32; off > 0; off >>= 1) ss += __shfl_down(ss, off, 64);
    __shared__ float red[4];
    int lane = tid & 63, w = tid >> 6;
    if (lane == 0) red[w] = ss;
    __syncthreads();
    float rs = rsqrtf((red[0] + red[1] + red[2] + red[3]) * (1.f / D) + 1e-5f);
    u16* up = qku + (size_t)row * NQKU + 4096 + col;
    u16 ut[8];
    *(int4*)ut = *(const int4*)up;
    u16 o[8];
#pragma unroll
    for (int j = 0; j < 8; j++)
        o[j] = f2b(f[j] * rs * nw[col + j] * b2f(ut[j]));
    *(int4*)up = *(int4*)o;
}

extern "C" void kernel_launch(void* const* d_in, const int* in_sizes, int n_in,
                              void* d_out, int out_size, void* d_ws, size_t ws_size,
                              hipStream_t stream) {
    const float* x  = (const float*)d_in[0];
    const float* fc = (const float*)d_in[1];
    const float* fs = (const float*)d_in[2];
    const float* wq = (const float*)d_in[3];
    const float* wk = (const float*)d_in[4];
    const float* wv = (const float*)d_in[5];
    const float* wu = (const float*)d_in[6];
    const float* wo = (const float*)d_in[7];
    const float* nw = (const float*)d_in[8];
    float* out = (float*)d_out;

    char* ws = (char*)d_ws;
    const size_t WSZ = (size_t)D * D * sizeof(u16);      // 8.39 MB
    // layout (WSZ units): h[0,2) wT[2,7) qku[7,13) vt[13,15) k_r[15,17) q_r[17,19)
    u16* h_b  = (u16*)(ws);
    u16* wT   = (u16*)(ws + 2 * WSZ);                    // rows: q,k,u,v,o
    u16* qku  = (u16*)(ws + 7 * WSZ);                    // M x 6144 (att cols 0..2047, u at 4096)
    u16* vt   = (u16*)(ws + 13 * WSZ);                   // tiled+pre-swizzled V
    u16* k_r  = (u16*)(ws + 15 * WSZ);                   // (B,H,S,HD)
    u16* q_r  = (u16*)(ws + 17 * WSZ);                   // (B,H,S,HD)

    silu_cast<<<M * D / 1024, 256, 0, stream>>>(x, h_b, M * D);
    wcast5<<<dim3(32, 32, 5), 256, 0, stream>>>(wq, wk, wu, wv, wo, wT);

    // fused QKUV GEMM with RoPE'd q,k epilogue
    gemm_qkuv<<<512, 512, 0, stream>>>(h_b, wT, qku, vt, q_r, k_r, fc, fs);

    hstu_attn<<<256, 512, 0, stream>>>(q_r, k_r, vt, qku);
    rms_mul<<<M, 256, 0, stream>>>(qku, nw);
    gemm_bt_f32<<<dim3(D / 128, M / 128), 256, 0, stream>>>(
        qku + 4096, wT + 4 * (size_t)D * D, out, NQKU, D, D);
}